// Round 2
// baseline (563.094 us; speedup 1.0000x reference)
//
#include <hip/hip_runtime.h>

// Problem constants
#define D    128      // d+1
#define DM   127      // d
#define NP1  1024     // N+1
#define B    8
#define H    8
#define NL   4

// Workspace layout (float offsets)
#define WS_QF 0                        // [H][128][128] padded Q   (params[:,1])
#define WS_PT (WS_QF + H*D*D)          // [H][128][128] padded+transposed P (params[:,0]); Pt[k][j] = Pfull[j][k]
#define WS_G  (WS_PT + H*D*D)          // [B][128][128] Gram
#define WS_T  (WS_G  + B*D*D)          // [B][H][128][128] T = Qf @ G
#define WS_S  (WS_T  + B*H*D*D)        // [B][128][128] S = sum_h T @ Pt / N
// total = 1,572,864 floats = 6 MB

// ---------------------------------------------------------------------------
// Kernel 1: per layer, (a) pad/transpose params into Qf/Pt, (b) G_b = Z^T M Z
// grid (16 slices, B), 256 threads. Block (s,b) computes G rows [8s, 8s+8).
// ---------------------------------------------------------------------------
__global__ __launch_bounds__(256) void g_kernel(
    const float* __restrict__ Z, const float* __restrict__ ap,
    float* __restrict__ Qf, float* __restrict__ Pt, float* __restrict__ G)
{
    const int s = blockIdx.x;   // 0..15
    const int b = blockIdx.y;   // 0..7
    const int t = threadIdx.x;

    // --- prologue: pad Q -> Qf, pad+transpose P -> Pt (one-time per layer) ---
    // Reference: params[:, 0] = P, params[:, 1] = Q.
    {
        const int blockflat = s + 16 * b;           // 0..127
        const int base = blockflat * 2048 + t * 8;  // 128 blocks * 2048 = 262144 elems
        #pragma unroll
        for (int e = 0; e < 8; ++e) {
            const int idx   = base + e;
            const int isP   = idx >> 17;        // 131072 Qf elems, then 131072 Pt
            const int local = idx & 131071;
            const int h = local >> 14;
            const int r = (local >> 7) & 127;
            const int c = local & 127;
            if (!isP) {
                // Qf[h][r][c]: zero-padded; Q = params[:,1] -> slot index 1
                float v = (r < DM && c < DM) ? ap[(h*2 + 1)*DM*DM + r*DM + c] : 0.f;
                Qf[local] = v;
            } else {
                // Pt[h][k=r][j=c] = Pfull[j][k]; P = params[:,0] -> slot 0; corner Pfull[127][127]=1
                float v;
                if (r < DM && c < DM)        v = ap[(h*2 + 0)*DM*DM + c*DM + r];
                else if (r == DM && c == DM) v = 1.f;
                else                         v = 0.f;
                Pt[local] = v;
            }
        }
    }

    // --- G_b rows [8s, 8s+8), accumulating over tokens n=0..1022 ---
    const int ty = t >> 5;      // 0..7  -> local row
    const int tx = t & 31;      // 0..31 -> 4 cols each
    const int i  = s * 8 + ty;
    const int j0 = tx * 4;

    __shared__ float zc[8 * 128];  // one 8-token chunk of Z_b
    float a0 = 0.f, a1 = 0.f, a2 = 0.f, a3 = 0.f;
    const float* Zb = Z + (size_t)b * NP1 * D;

    for (int c = 0; c < 128; ++c) {
        __syncthreads();
        float4 v = ((const float4*)(Zb + c * 8 * D))[t];
        if (c == 127 && t >= 224) v = make_float4(0.f, 0.f, 0.f, 0.f);  // mask token 1023
        ((float4*)zc)[t] = v;
        __syncthreads();
        #pragma unroll
        for (int nn = 0; nn < 8; ++nn) {
            const float  zi = zc[nn * 128 + i];
            const float4 zj = *(const float4*)&zc[nn * 128 + j0];
            a0 += zi * zj.x; a1 += zi * zj.y; a2 += zi * zj.z; a3 += zi * zj.w;
        }
    }
    *(float4*)&G[b * D * D + i * D + j0] = make_float4(a0, a1, a2, a3);
}

// ---------------------------------------------------------------------------
// Kernel 2: T[b][h] = Qf[h] @ G[b]
// grid (8 slices, H, B), 256 threads. Block computes T rows [16s, 16s+16).
// ---------------------------------------------------------------------------
__global__ __launch_bounds__(256) void t_kernel(
    const float* __restrict__ Qf, const float* __restrict__ G, float* __restrict__ T)
{
    const int s = blockIdx.x;   // 0..7
    const int h = blockIdx.y;
    const int b = blockIdx.z;
    const int t = threadIdx.x;
    const int ty = t >> 4;      // 0..15 -> local row
    const int tx = t & 15;      // 0..15 -> 8 cols each
    const int j0 = tx * 8;

    __shared__ float Qs[16 * 128];
    __shared__ float Gc[16 * 128];

    const float* Qh = Qf + (h * D + s * 16) * D;
    ((float4*)Qs)[t]       = ((const float4*)Qh)[t];
    ((float4*)Qs)[256 + t] = ((const float4*)Qh)[256 + t];

    float acc[8] = {0.f,0.f,0.f,0.f,0.f,0.f,0.f,0.f};
    const float* Gb = G + b * D * D;

    for (int kc = 0; kc < 8; ++kc) {
        __syncthreads();
        ((float4*)Gc)[t]       = ((const float4*)(Gb + kc * 16 * D))[t];
        ((float4*)Gc)[256 + t] = ((const float4*)(Gb + kc * 16 * D))[256 + t];
        __syncthreads();
        #pragma unroll
        for (int kk = 0; kk < 16; ++kk) {
            const float  q  = Qs[ty * 128 + kc * 16 + kk];
            const float4 g0 = *(const float4*)&Gc[kk * 128 + j0];
            const float4 g1 = *(const float4*)&Gc[kk * 128 + j0 + 4];
            acc[0] += q * g0.x; acc[1] += q * g0.y; acc[2] += q * g0.z; acc[3] += q * g0.w;
            acc[4] += q * g1.x; acc[5] += q * g1.y; acc[6] += q * g1.z; acc[7] += q * g1.w;
        }
    }
    float* Tout = T + (((b * H + h) * D) + s * 16 + ty) * D + j0;
    *(float4*)Tout       = make_float4(acc[0], acc[1], acc[2], acc[3]);
    *(float4*)(Tout + 4) = make_float4(acc[4], acc[5], acc[6], acc[7]);
}

// ---------------------------------------------------------------------------
// Kernel 3: S[b] = (1/N) * sum_h T[b][h] @ Pt[h]   (Pt already transposed)
// grid (16 slices, B), 256 threads. Block computes S rows [8s, 8s+8).
// ---------------------------------------------------------------------------
__global__ __launch_bounds__(256) void s_kernel(
    const float* __restrict__ T, const float* __restrict__ Pt, float* __restrict__ S)
{
    const int s = blockIdx.x;   // 0..15
    const int b = blockIdx.y;
    const int t = threadIdx.x;
    const int ty = t >> 5;      // 0..7
    const int tx = t & 31;      // 4 cols each
    const int j0 = tx * 4;

    __shared__ float Ts[8 * 128];
    __shared__ float Pc[16 * 128];

    float a0 = 0.f, a1 = 0.f, a2 = 0.f, a3 = 0.f;

    for (int h = 0; h < H; ++h) {
        const float* Tbh = T + (((b * H + h) * D) + s * 8) * D;
        const float* Ph  = Pt + h * D * D;
        for (int kc = 0; kc < 8; ++kc) {
            __syncthreads();
            if (kc == 0) ((float4*)Ts)[t] = ((const float4*)Tbh)[t];
            ((float4*)Pc)[t]       = ((const float4*)(Ph + kc * 16 * D))[t];
            ((float4*)Pc)[256 + t] = ((const float4*)(Ph + kc * 16 * D))[256 + t];
            __syncthreads();
            #pragma unroll
            for (int kk = 0; kk < 16; ++kk) {
                const float  tv = Ts[ty * 128 + kc * 16 + kk];
                const float4 p  = *(const float4*)&Pc[kk * 128 + j0];
                a0 += tv * p.x; a1 += tv * p.y; a2 += tv * p.z; a3 += tv * p.w;
            }
        }
    }
    const float inv = 1.0f / 1023.0f;
    *(float4*)&S[b * D * D + (s * 8 + ty) * D + j0] =
        make_float4(a0 * inv, a1 * inv, a2 * inv, a3 * inv);
}

// ---------------------------------------------------------------------------
// Kernel 4: Zout[b] = Zin[b] + Zin[b] @ S[b]    (row-exclusive => in-place safe)
// grid (32 slices, B), 256 threads. Block computes 32 rows.
// ---------------------------------------------------------------------------
__global__ __launch_bounds__(256) void z_kernel(
    const float* __restrict__ Zin, const float* __restrict__ S, float* __restrict__ Zout)
{
    const int s = blockIdx.x;   // 0..31
    const int b = blockIdx.y;
    const int t = threadIdx.x;
    const int ty = t >> 3;      // 0..31 -> row
    const int tx = t & 7;       // 16 cols each
    const int j0 = tx * 16;

    __shared__ float Zs[32 * 132];   // padded stride (avoid same-bank on column read)
    __shared__ float Sc[32 * 128];   // 32-row chunk of S

    const float* Zrow0 = Zin + ((size_t)b * NP1 + s * 32) * D;
    for (int q = t; q < 32 * 32; q += 256) {
        const int r = q >> 5, c4 = q & 31;
        *(float4*)&Zs[r * 132 + c4 * 4] = ((const float4*)(Zrow0 + r * D))[c4];
    }

    float acc[16];
    #pragma unroll
    for (int q = 0; q < 16; ++q) acc[q] = 0.f;

    const float* Sb = S + b * D * D;
    for (int kc = 0; kc < 4; ++kc) {
        __syncthreads();
        ((float4*)Sc)[t]       = ((const float4*)(Sb + kc * 32 * D))[t];
        ((float4*)Sc)[256 + t] = ((const float4*)(Sb + kc * 32 * D))[256 + t];
        ((float4*)Sc)[512 + t] = ((const float4*)(Sb + kc * 32 * D))[512 + t];
        ((float4*)Sc)[768 + t] = ((const float4*)(Sb + kc * 32 * D))[768 + t];
        __syncthreads();
        #pragma unroll
        for (int kk = 0; kk < 32; ++kk) {
            const float zv = Zs[ty * 132 + kc * 32 + kk];
            #pragma unroll
            for (int jj = 0; jj < 4; ++jj) {
                const float4 sv = *(const float4*)&Sc[kk * 128 + j0 + jj * 4];
                acc[jj * 4 + 0] += zv * sv.x;
                acc[jj * 4 + 1] += zv * sv.y;
                acc[jj * 4 + 2] += zv * sv.z;
                acc[jj * 4 + 3] += zv * sv.w;
            }
        }
    }

    float* Orow = Zout + ((size_t)b * NP1 + s * 32 + ty) * D + j0;
    #pragma unroll
    for (int jj = 0; jj < 4; ++jj) {
        float4 o;
        o.x = Zs[ty * 132 + j0 + jj * 4 + 0] + acc[jj * 4 + 0];
        o.y = Zs[ty * 132 + j0 + jj * 4 + 1] + acc[jj * 4 + 1];
        o.z = Zs[ty * 132 + j0 + jj * 4 + 2] + acc[jj * 4 + 2];
        o.w = Zs[ty * 132 + j0 + jj * 4 + 3] + acc[jj * 4 + 3];
        *(float4*)(Orow + jj * 4) = o;
    }
}

// ---------------------------------------------------------------------------
extern "C" void kernel_launch(void* const* d_in, const int* in_sizes, int n_in,
                              void* d_out, int out_size, void* d_ws, size_t ws_size,
                              hipStream_t stream)
{
    const float* Z0 = (const float*)d_in[0];
    const float* ap = (const float*)d_in[1];
    float* out = (float*)d_out;
    float* ws  = (float*)d_ws;

    float* Qf = ws + WS_QF;
    float* Pt = ws + WS_PT;
    float* G  = ws + WS_G;
    float* T  = ws + WS_T;
    float* S  = ws + WS_S;

    const float* Zcur = Z0;
    for (int l = 0; l < NL; ++l) {
        const float* apl = ap + (size_t)l * H * 2 * DM * DM;
        hipLaunchKernelGGL(g_kernel, dim3(16, B), dim3(256), 0, stream, Zcur, apl, Qf, Pt, G);
        hipLaunchKernelGGL(t_kernel, dim3(8, H, B), dim3(256), 0, stream, Qf, G, T);
        hipLaunchKernelGGL(s_kernel, dim3(16, B), dim3(256), 0, stream, T, Pt, S);
        hipLaunchKernelGGL(z_kernel, dim3(32, B), dim3(256), 0, stream, Zcur, S, out);
        Zcur = out;
    }
}

// Round 3
// 251.323 us; speedup vs baseline: 2.2405x; 2.2405x over previous
//
#include <hip/hip_runtime.h>

// Problem constants
#define D    128      // d+1
#define DM   127      // d
#define NP1  1024     // N+1
#define B    8
#define H    8
#define NL   4

// Workspace layout (float offsets) — 1,572,864 floats = 6 MB total
#define WS_QF 0                        // [H][128][128] padded Q   (params[:,1])
#define WS_PT (WS_QF + H*D*D)          // [H][128][128] padded+transposed P (params[:,0])
#define WS_G  (WS_PT + H*D*D)          // [B][128][128] reduced Gram
#define WS_GS (WS_G  + B*D*D)          // [B][8][128][128] shared buffer: Gp partials, then Sp partials
#define WS_S  (WS_GS + B*8*D*D)        // [B][128][128] S = (1/N) sum_h Sp

// ---------------------------------------------------------------------------
// Kernel 1: partial Grams. grid (8 chunks, 4 col-quarters, B) = 256 blocks.
// Block (c,q,b): Gp[b][c][0:128][32q:32q+32] = sum_{k in chunk} z_k z_k^T
// Stage the whole 128-token chunk in LDS once; no barriers in the K loop.
// ---------------------------------------------------------------------------
__global__ __launch_bounds__(256) void gp_kernel(
    const float* __restrict__ Z, float* __restrict__ Gp)
{
    const int c = blockIdx.x;   // token chunk 0..7 (128 tokens each)
    const int q = blockIdx.y;   // col quarter 0..3
    const int b = blockIdx.z;
    const int t = threadIdx.x;

    __shared__ float Zs[128 * 128];   // 64 KB: chunk tokens (rows) x dims (cols)

    const float4* src = (const float4*)(Z + ((size_t)b * NP1 + c * 128) * D);
    #pragma unroll
    for (int i = 0; i < 16; ++i) {
        float4 v = src[t + 256 * i];
        // token 1023 = last row of chunk 7 -> masked (key mask)
        if (c == 7 && i == 15 && t >= 224) v = make_float4(0.f, 0.f, 0.f, 0.f);
        ((float4*)Zs)[t + 256 * i] = v;
    }
    __syncthreads();

    const int ty = t >> 3;            // 0..31 -> rows i0 = 4*ty
    const int tx = t & 7;             // 0..7  -> cols j0 = 32q + 4*tx
    const int i0 = ty * 4;
    const int j0 = q * 32 + tx * 4;

    float acc[4][4] = {};
    #pragma unroll 4
    for (int k = 0; k < 128; ++k) {
        const float4 a = *(const float4*)&Zs[k * 128 + i0];   // banks 4ty: conflict-free
        const float4 cc = *(const float4*)&Zs[k * 128 + j0];  // banks 4tx: conflict-free
        acc[0][0] += a.x * cc.x; acc[0][1] += a.x * cc.y; acc[0][2] += a.x * cc.z; acc[0][3] += a.x * cc.w;
        acc[1][0] += a.y * cc.x; acc[1][1] += a.y * cc.y; acc[1][2] += a.y * cc.z; acc[1][3] += a.y * cc.w;
        acc[2][0] += a.z * cc.x; acc[2][1] += a.z * cc.y; acc[2][2] += a.z * cc.z; acc[2][3] += a.z * cc.w;
        acc[3][0] += a.w * cc.x; acc[3][1] += a.w * cc.y; acc[3][2] += a.w * cc.z; acc[3][3] += a.w * cc.w;
    }

    float* Gb = Gp + ((size_t)(b * 8 + c)) * D * D;
    #pragma unroll
    for (int r = 0; r < 4; ++r) {
        *(float4*)&Gb[(i0 + r) * D + j0] =
            make_float4(acc[r][0], acc[r][1], acc[r][2], acc[r][3]);
    }
}

// ---------------------------------------------------------------------------
// Kernel 2: (a) pad/transpose params -> Qf, Pt; (b) G[b] = sum_c Gp[b][c].
// grid (16, B) = 128 blocks.
// ---------------------------------------------------------------------------
__global__ __launch_bounds__(256) void prep_reduce_kernel(
    const float* __restrict__ ap, const float* __restrict__ Gp,
    float* __restrict__ Qf, float* __restrict__ Pt, float* __restrict__ G)
{
    const int sx = blockIdx.x;  // 0..15
    const int b  = blockIdx.y;  // 0..7
    const int t  = threadIdx.x;

    // --- param prep (reference: params[:,0]=P, params[:,1]=Q) ---
    {
        const int blockflat = sx + 16 * b;          // 0..127
        const int base = blockflat * 2048 + t * 8;
        #pragma unroll
        for (int e = 0; e < 8; ++e) {
            const int idx   = base + e;
            const int isP   = idx >> 17;
            const int local = idx & 131071;
            const int h = local >> 14;
            const int r = (local >> 7) & 127;
            const int c = local & 127;
            if (!isP) {
                float v = (r < DM && c < DM) ? ap[(h*2 + 1)*DM*DM + r*DM + c] : 0.f;
                Qf[local] = v;
            } else {
                float v;
                if (r < DM && c < DM)        v = ap[(h*2 + 0)*DM*DM + c*DM + r];
                else if (r == DM && c == DM) v = 1.f;
                else                         v = 0.f;
                Pt[local] = v;
            }
        }
    }

    // --- G reduce: each thread one float4 ---
    const int idx4 = sx * 256 + t;                  // 0..4095 per b
    float4 sum = make_float4(0.f, 0.f, 0.f, 0.f);
    #pragma unroll
    for (int c = 0; c < 8; ++c) {
        const float4 v = ((const float4*)Gp)[(size_t)(b * 8 + c) * 4096 + idx4];
        sum.x += v.x; sum.y += v.y; sum.z += v.z; sum.w += v.w;
    }
    ((float4*)G)[(size_t)b * 4096 + idx4] = sum;
}

// ---------------------------------------------------------------------------
// Kernel 3: fused T=Qf@G then Sp[b][h]=T@Pt. grid (4 slices, H, B) = 256 blocks.
// Block (s,h,b) computes rows [32s,32s+32) of Sp[b][h].
// ---------------------------------------------------------------------------
__global__ __launch_bounds__(256) void ts_kernel(
    const float* __restrict__ Qf, const float* __restrict__ Pt,
    const float* __restrict__ G, float* __restrict__ Sp)
{
    const int s = blockIdx.x;   // 0..3
    const int h = blockIdx.y;
    const int b = blockIdx.z;
    const int t = threadIdx.x;
    const int ty = t >> 4;      // 0..15 -> rows ty, ty+16 (local)
    const int tx = t & 15;      // cols 4tx..4tx+4 and 64+4tx..  (2-way banks: free)

    __shared__ float Qs[32 * 128];   // 16 KB
    __shared__ float Cc[16 * 128];   // 8 KB (G / Pt chunk)
    __shared__ float Ts[32 * 128];   // 16 KB

    const float4* qsrc = (const float4*)(Qf + ((size_t)h * D + s * 32) * D);
    #pragma unroll
    for (int i = 0; i < 4; ++i) ((float4*)Qs)[t + 256 * i] = qsrc[t + 256 * i];

    const int j0 = 4 * tx;
    const int j1 = 64 + 4 * tx;

    // ---- phase 1: T rows = Qs @ G[b] ----
    float acc[2][8] = {};
    const float* Gb = G + (size_t)b * D * D;
    for (int kc = 0; kc < 8; ++kc) {
        __syncthreads();
        ((float4*)Cc)[t]       = ((const float4*)(Gb + kc * 16 * D))[t];
        ((float4*)Cc)[256 + t] = ((const float4*)(Gb + kc * 16 * D))[256 + t];
        __syncthreads();
        #pragma unroll
        for (int kk = 0; kk < 16; ++kk) {
            const float q0 = Qs[ty * 128 + kc * 16 + kk];
            const float q1 = Qs[(ty + 16) * 128 + kc * 16 + kk];
            const float4 g0 = *(const float4*)&Cc[kk * 128 + j0];
            const float4 g1 = *(const float4*)&Cc[kk * 128 + j1];
            acc[0][0] += q0 * g0.x; acc[0][1] += q0 * g0.y; acc[0][2] += q0 * g0.z; acc[0][3] += q0 * g0.w;
            acc[0][4] += q0 * g1.x; acc[0][5] += q0 * g1.y; acc[0][6] += q0 * g1.z; acc[0][7] += q0 * g1.w;
            acc[1][0] += q1 * g0.x; acc[1][1] += q1 * g0.y; acc[1][2] += q1 * g0.z; acc[1][3] += q1 * g0.w;
            acc[1][4] += q1 * g1.x; acc[1][5] += q1 * g1.y; acc[1][6] += q1 * g1.z; acc[1][7] += q1 * g1.w;
        }
    }
    *(float4*)&Ts[ty * 128 + j0]        = make_float4(acc[0][0], acc[0][1], acc[0][2], acc[0][3]);
    *(float4*)&Ts[ty * 128 + j1]        = make_float4(acc[0][4], acc[0][5], acc[0][6], acc[0][7]);
    *(float4*)&Ts[(ty + 16) * 128 + j0] = make_float4(acc[1][0], acc[1][1], acc[1][2], acc[1][3]);
    *(float4*)&Ts[(ty + 16) * 128 + j1] = make_float4(acc[1][4], acc[1][5], acc[1][6], acc[1][7]);

    // ---- phase 2: Sp rows = Ts @ Pt[h] ----
    float bcc[2][8] = {};
    const float* Ph = Pt + (size_t)h * D * D;
    for (int kc = 0; kc < 8; ++kc) {
        __syncthreads();   // also covers Ts-write visibility on kc==0
        ((float4*)Cc)[t]       = ((const float4*)(Ph + kc * 16 * D))[t];
        ((float4*)Cc)[256 + t] = ((const float4*)(Ph + kc * 16 * D))[256 + t];
        __syncthreads();
        #pragma unroll
        for (int kk = 0; kk < 16; ++kk) {
            const float t0 = Ts[ty * 128 + kc * 16 + kk];
            const float t1 = Ts[(ty + 16) * 128 + kc * 16 + kk];
            const float4 p0 = *(const float4*)&Cc[kk * 128 + j0];
            const float4 p1 = *(const float4*)&Cc[kk * 128 + j1];
            bcc[0][0] += t0 * p0.x; bcc[0][1] += t0 * p0.y; bcc[0][2] += t0 * p0.z; bcc[0][3] += t0 * p0.w;
            bcc[0][4] += t0 * p1.x; bcc[0][5] += t0 * p1.y; bcc[0][6] += t0 * p1.z; bcc[0][7] += t0 * p1.w;
            bcc[1][0] += t1 * p0.x; bcc[1][1] += t1 * p0.y; bcc[1][2] += t1 * p0.z; bcc[1][3] += t1 * p0.w;
            bcc[1][4] += t1 * p1.x; bcc[1][5] += t1 * p1.y; bcc[1][6] += t1 * p1.z; bcc[1][7] += t1 * p1.w;
        }
    }
    float* Sb = Sp + ((size_t)(b * 8 + h)) * D * D;
    const int r0 = s * 32 + ty;
    const int r1 = r0 + 16;
    *(float4*)&Sb[r0 * D + j0] = make_float4(bcc[0][0], bcc[0][1], bcc[0][2], bcc[0][3]);
    *(float4*)&Sb[r0 * D + j1] = make_float4(bcc[0][4], bcc[0][5], bcc[0][6], bcc[0][7]);
    *(float4*)&Sb[r1 * D + j0] = make_float4(bcc[1][0], bcc[1][1], bcc[1][2], bcc[1][3]);
    *(float4*)&Sb[r1 * D + j1] = make_float4(bcc[1][4], bcc[1][5], bcc[1][6], bcc[1][7]);
}

// ---------------------------------------------------------------------------
// Kernel 4: S[b] = (1/N) * sum_h Sp[b][h]. grid (16, B) = 128 blocks.
// ---------------------------------------------------------------------------
__global__ __launch_bounds__(256) void sred_kernel(
    const float* __restrict__ Sp, float* __restrict__ S)
{
    const int b = blockIdx.y;
    const int idx4 = blockIdx.x * 256 + threadIdx.x;   // 0..4095 per b
    float4 sum = make_float4(0.f, 0.f, 0.f, 0.f);
    #pragma unroll
    for (int h = 0; h < 8; ++h) {
        const float4 v = ((const float4*)Sp)[(size_t)(b * 8 + h) * 4096 + idx4];
        sum.x += v.x; sum.y += v.y; sum.z += v.z; sum.w += v.w;
    }
    const float inv = 1.0f / 1023.0f;
    ((float4*)S)[(size_t)b * 4096 + idx4] =
        make_float4(sum.x * inv, sum.y * inv, sum.z * inv, sum.w * inv);
}

// ---------------------------------------------------------------------------
// Kernel 5: Zout = Zin + Zin @ S.  grid (32, B) = 256 blocks.
// Column map 4tx + 32jj -> conflict-free LDS banks on Sc reads.
// ---------------------------------------------------------------------------
__global__ __launch_bounds__(256) void z_kernel(
    const float* __restrict__ Zin, const float* __restrict__ S, float* __restrict__ Zout)
{
    const int s = blockIdx.x;   // 0..31
    const int b = blockIdx.y;
    const int t = threadIdx.x;
    const int ty = t >> 3;      // 0..31 -> row
    const int tx = t & 7;       // cols 4tx + 32jj, jj=0..3

    __shared__ float Zs[32 * 132];
    __shared__ float Sc[32 * 128];

    const float* Zrow0 = Zin + ((size_t)b * NP1 + s * 32) * D;
    for (int q = t; q < 32 * 32; q += 256) {
        const int r = q >> 5, c4 = q & 31;
        *(float4*)&Zs[r * 132 + c4 * 4] = ((const float4*)(Zrow0 + r * D))[c4];
    }

    float acc[16];
    #pragma unroll
    for (int q = 0; q < 16; ++q) acc[q] = 0.f;

    const float* Sb = S + (size_t)b * D * D;
    for (int kc = 0; kc < 4; ++kc) {
        __syncthreads();
        ((float4*)Sc)[t]       = ((const float4*)(Sb + kc * 32 * D))[t];
        ((float4*)Sc)[256 + t] = ((const float4*)(Sb + kc * 32 * D))[256 + t];
        ((float4*)Sc)[512 + t] = ((const float4*)(Sb + kc * 32 * D))[512 + t];
        ((float4*)Sc)[768 + t] = ((const float4*)(Sb + kc * 32 * D))[768 + t];
        __syncthreads();
        #pragma unroll
        for (int kk = 0; kk < 32; ++kk) {
            const float zv = Zs[ty * 132 + kc * 32 + kk];
            #pragma unroll
            for (int jj = 0; jj < 4; ++jj) {
                const float4 sv = *(const float4*)&Sc[kk * 128 + 4 * tx + 32 * jj];
                acc[jj * 4 + 0] += zv * sv.x;
                acc[jj * 4 + 1] += zv * sv.y;
                acc[jj * 4 + 2] += zv * sv.z;
                acc[jj * 4 + 3] += zv * sv.w;
            }
        }
    }

    float* Orow = Zout + ((size_t)b * NP1 + s * 32 + ty) * D;
    #pragma unroll
    for (int jj = 0; jj < 4; ++jj) {
        const int col = 4 * tx + 32 * jj;
        const float4 zr = *(const float4*)&Zs[ty * 132 + col];
        float4 o;
        o.x = zr.x + acc[jj * 4 + 0];
        o.y = zr.y + acc[jj * 4 + 1];
        o.z = zr.z + acc[jj * 4 + 2];
        o.w = zr.w + acc[jj * 4 + 3];
        *(float4*)(Orow + col) = o;
    }
}

// ---------------------------------------------------------------------------
extern "C" void kernel_launch(void* const* d_in, const int* in_sizes, int n_in,
                              void* d_out, int out_size, void* d_ws, size_t ws_size,
                              hipStream_t stream)
{
    const float* Z0 = (const float*)d_in[0];
    const float* ap = (const float*)d_in[1];
    float* out = (float*)d_out;
    float* ws  = (float*)d_ws;

    float* Qf = ws + WS_QF;
    float* Pt = ws + WS_PT;
    float* G  = ws + WS_G;
    float* GS = ws + WS_GS;   // Gp then Sp (disjoint lifetimes within a layer)
    float* S  = ws + WS_S;

    const float* Zcur = Z0;
    for (int l = 0; l < NL; ++l) {
        const float* apl = ap + (size_t)l * H * 2 * DM * DM;
        hipLaunchKernelGGL(gp_kernel,          dim3(8, 4, B), dim3(256), 0, stream, Zcur, GS);
        hipLaunchKernelGGL(prep_reduce_kernel, dim3(16, B),   dim3(256), 0, stream, apl, GS, Qf, Pt, G);
        hipLaunchKernelGGL(ts_kernel,          dim3(4, H, B), dim3(256), 0, stream, Qf, Pt, G, GS);
        hipLaunchKernelGGL(sred_kernel,        dim3(16, B),   dim3(256), 0, stream, GS, S);
        hipLaunchKernelGGL(z_kernel,           dim3(32, B),   dim3(256), 0, stream, Zcur, S, out);
        Zcur = out;
    }
}